// Round 2
// baseline (833.371 us; speedup 1.0000x reference)
//
#include <hip/hip_runtime.h>
#include <hip/hip_bf16.h>

#define N_NODES 100000
#define C_DIM   160
#define R_REL   10
#define B_BLK   5
#define CB      32
#define E_EDGES 500000
#define NB      16      // nodes per block in layer kernel
#define ASTRIDE 1768    // ushorts per node row in LDS (1760 data + 8 pad -> 221*16B, conflict-free)

typedef float f32x4 __attribute__((ext_vector_type(4)));
typedef short s16x8 __attribute__((ext_vector_type(8)));

__device__ __forceinline__ float b2f(unsigned short h){ return __uint_as_float(((unsigned)h)<<16); }
__device__ __forceinline__ unsigned short f2b(float f){
  unsigned b = __float_as_uint(f);
  b += 0x7FFFu + ((b>>16)&1u);            // round-to-nearest-even
  return (unsigned short)(b>>16);
}

// ---------------- CSR build ----------------
__global__ __launch_bounds__(256) void k_count(const int* __restrict__ dst, int* __restrict__ deg){
  int e = blockIdx.x*256 + threadIdx.x;
  if (e < E_EDGES) atomicAdd(&deg[dst[e]], 1);
}

__global__ __launch_bounds__(256) void k_scan1(const int* __restrict__ deg, int* __restrict__ rowptr,
                                               int* __restrict__ sums){
  __shared__ int lds[256];
  const int t = threadIdx.x;
  const int base = blockIdx.x*4096 + t*16;
  int v[16]; int tot = 0;
  #pragma unroll
  for (int i=0;i<16;++i){
    int idx = base+i;
    int d = (idx < N_NODES) ? deg[idx] : 0;
    v[i] = tot; tot += d;
  }
  lds[t] = tot;
  __syncthreads();
  for (int off=1; off<256; off<<=1){
    int x = (t>=off) ? lds[t-off] : 0;
    __syncthreads();
    lds[t] += x;
    __syncthreads();
  }
  const int excl = lds[t] - tot;
  #pragma unroll
  for (int i=0;i<16;++i){
    int idx = base+i;
    if (idx < N_NODES) rowptr[idx] = excl + v[i];
  }
  if (t == 0) sums[blockIdx.x] = lds[255];
}

__global__ void k_scan2(int* __restrict__ sums, int* __restrict__ rowptr, int nchunks){
  if (threadIdx.x==0 && blockIdx.x==0){
    int run = 0;
    for (int b=0;b<nchunks;++b){ int s = sums[b]; sums[b] = run; run += s; }
    rowptr[N_NODES] = run;
  }
}

__global__ __launch_bounds__(256) void k_scan3(int* __restrict__ rowptr, int* __restrict__ cursor,
                                               const int* __restrict__ sums){
  int i = blockIdx.x*256 + threadIdx.x;
  if (i < N_NODES){
    int v = rowptr[i] + sums[i>>12];
    rowptr[i] = v;
    cursor[i] = v;
  }
}

__global__ __launch_bounds__(256) void k_scatter(const int* __restrict__ src, const int* __restrict__ dst,
                                                 const int* __restrict__ et, int* __restrict__ cursor,
                                                 int* __restrict__ srcs, int* __restrict__ rels){
  int e = blockIdx.x*256 + threadIdx.x;
  if (e < E_EDGES){
    int d = dst[e];
    int pos = atomicAdd(&cursor[d], 1);
    srcs[pos] = src[e];
    rels[pos] = et[e];
  }
}

// ---------------- weight repack: B-fragment layout ----------------
// wp[((ct*15+ko)*64+lane)*8 + j] = B[k][col] with col = ct*16+(lane&15), k = ko*32+(lane>>4)*8+j
// k < 320: mean part (r = ko, cl = k%32), block b = col/32, d = col%32 -> w[r][b][cl][d]
// k >= 320: root part ci = k-320 -> root[ci][col]
__global__ __launch_bounds__(256) void k_wpack(const float* __restrict__ w, const float* __restrict__ root,
                                               unsigned short* __restrict__ wp){
  int tid = blockIdx.x*256 + threadIdx.x;
  if (tid >= 10*15*64) return;
  const int l  = tid & 63;
  const int ko = (tid>>6) % 15;
  const int ct = tid / (15*64);
  const int col16 = l & 15, kq = l >> 4;
  const int cout = ct*16 + col16;
  const int b = cout >> 5, d = cout & 31;
  unsigned short* dstp = wp + (size_t)tid*8;
  #pragma unroll
  for (int j=0;j<8;++j){
    float f;
    if (ko < 10){
      int cl = kq*8 + j;
      f = w[((ko*B_BLK + b)*CB + cl)*CB + d];
    } else {
      int ci = (ko-10)*32 + kq*8 + j;
      f = root[ci*C_DIM + cout];
    }
    dstp[j] = f2b(f);
  }
}

// ---------------- fused layer: aggregate + mean + (blockdiag ⊕ root) GEMM via MFMA ----------------
template<int XF32, int RELU>
__global__ __launch_bounds__(256) void k_layer(
    const float* __restrict__ xf,            // fp32 features (layer 1)
    const unsigned short* __restrict__ xb,   // bf16 features (layer 2)
    const int* __restrict__ rowptr,
    const int* __restrict__ srcs,
    const int* __restrict__ rels,
    const unsigned short* __restrict__ wpack,
    const float* __restrict__ bias,
    float* __restrict__ outf,
    unsigned short* __restrict__ outb)
{
  __shared__ unsigned short A[NB*ASTRIDE];
  const int tid  = threadIdx.x;
  const int wave = tid >> 6;
  const int lane = tid & 63;
  const int nb   = blockIdx.x * NB;

  // ---- Phase A: per-wave aggregation of 4 nodes; lane covers channel pairs {2l,2l+1} and (l<16) {128+2l,129+2l}
  for (int mi = 0; mi < 4; ++mi) {
    const int m = wave*4 + mi;
    const int n = nb + m;
    const int e0 = rowptr[n];
    const int e1 = rowptr[n+1];
    float4 acc[10];
    float  cnt[10];
    #pragma unroll
    for (int r=0;r<10;++r){ acc[r] = make_float4(0.f,0.f,0.f,0.f); cnt[r] = 0.f; }

    for (int e=e0; e<e1; ++e){
      const int s = srcs[e];
      const int r = rels[e];
      float v0, v1, v2 = 0.f, v3 = 0.f;
      if (XF32){
        const float2* p = (const float2*)(xf + (size_t)s*C_DIM);
        float2 u0 = p[lane]; v0 = u0.x; v1 = u0.y;
        if (lane < 16){ float2 u1 = p[64+lane]; v2 = u1.x; v3 = u1.y; }
      } else {
        const unsigned* p = (const unsigned*)(xb + (size_t)s*C_DIM);
        unsigned u0 = p[lane]; v0 = b2f(u0 & 0xFFFF); v1 = b2f(u0 >> 16);
        if (lane < 16){ unsigned u1 = p[64+lane]; v2 = b2f(u1 & 0xFFFF); v3 = b2f(u1 >> 16); }
      }
      switch(r){   // r is wave-uniform -> scalar branch; acc indices compile-time (no scratch)
        case 0: acc[0].x+=v0; acc[0].y+=v1; acc[0].z+=v2; acc[0].w+=v3; cnt[0]+=1.f; break;
        case 1: acc[1].x+=v0; acc[1].y+=v1; acc[1].z+=v2; acc[1].w+=v3; cnt[1]+=1.f; break;
        case 2: acc[2].x+=v0; acc[2].y+=v1; acc[2].z+=v2; acc[2].w+=v3; cnt[2]+=1.f; break;
        case 3: acc[3].x+=v0; acc[3].y+=v1; acc[3].z+=v2; acc[3].w+=v3; cnt[3]+=1.f; break;
        case 4: acc[4].x+=v0; acc[4].y+=v1; acc[4].z+=v2; acc[4].w+=v3; cnt[4]+=1.f; break;
        case 5: acc[5].x+=v0; acc[5].y+=v1; acc[5].z+=v2; acc[5].w+=v3; cnt[5]+=1.f; break;
        case 6: acc[6].x+=v0; acc[6].y+=v1; acc[6].z+=v2; acc[6].w+=v3; cnt[6]+=1.f; break;
        case 7: acc[7].x+=v0; acc[7].y+=v1; acc[7].z+=v2; acc[7].w+=v3; cnt[7]+=1.f; break;
        case 8: acc[8].x+=v0; acc[8].y+=v1; acc[8].z+=v2; acc[8].w+=v3; cnt[8]+=1.f; break;
        case 9: acc[9].x+=v0; acc[9].y+=v1; acc[9].z+=v2; acc[9].w+=v3; cnt[9]+=1.f; break;
      }
    }

    // means -> LDS (bf16), K-layout: [r*160 + c] for r<10, then x at [1600 + c]
    #pragma unroll
    for (int r=0;r<10;++r){
      const float s = (cnt[r] > 0.f) ? (1.0f / cnt[r]) : 0.f;
      unsigned p0 = (unsigned)f2b(acc[r].x*s) | ((unsigned)f2b(acc[r].y*s) << 16);
      *(unsigned*)&A[m*ASTRIDE + r*C_DIM + 2*lane] = p0;
      if (lane < 16){
        unsigned p1 = (unsigned)f2b(acc[r].z*s) | ((unsigned)f2b(acc[r].w*s) << 16);
        *(unsigned*)&A[m*ASTRIDE + r*C_DIM + 128 + 2*lane] = p1;
      }
    }
    if (XF32){
      const float2* p = (const float2*)(xf + (size_t)n*C_DIM);
      float2 u0 = p[lane];
      *(unsigned*)&A[m*ASTRIDE + 1600 + 2*lane] = (unsigned)f2b(u0.x) | ((unsigned)f2b(u0.y) << 16);
      if (lane < 16){
        float2 u1 = p[64+lane];
        *(unsigned*)&A[m*ASTRIDE + 1728 + 2*lane] = (unsigned)f2b(u1.x) | ((unsigned)f2b(u1.y) << 16);
      }
    } else {
      const unsigned* p = (const unsigned*)(xb + (size_t)n*C_DIM);
      *(unsigned*)&A[m*ASTRIDE + 1600 + 2*lane] = p[lane];
      if (lane < 16) *(unsigned*)&A[m*ASTRIDE + 1728 + 2*lane] = p[64+lane];
    }
  }
  __syncthreads();

  // ---- Phase B: per wave, col-tiles ct = wave, wave+4, wave+8 ; K = 480 (15 MFMA steps)
  const int row16 = lane & 15;   // A row (node) / D col
  const int kq    = lane >> 4;   // k-chunk
  for (int ct = wave; ct < 10; ct += 4){
    const int b = ct >> 1;
    f32x4 c = {0.f, 0.f, 0.f, 0.f};
    #pragma unroll
    for (int ko=0; ko<15; ++ko){
      const int aoff = row16*ASTRIDE + (ko < 10 ? ko*C_DIM + b*CB + kq*8
                                                : 1600 + (ko-10)*CB + kq*8);
      s16x8 af  = *(const s16x8*)&A[aoff];
      s16x8 bfv = *(const s16x8*)&wpack[(size_t)((ct*15+ko)*64 + lane)*8];
      c = __builtin_amdgcn_mfma_f32_16x16x32_bf16(af, bfv, c, 0, 0, 0);
    }
    const int col = ct*16 + row16;
    const float bv = bias[col];
    #pragma unroll
    for (int q=0;q<4;++q){
      const int n = nb + kq*4 + q;          // D row = (lane>>4)*4 + q
      float v = c[q] + bv;
      if (RELU) v = fmaxf(v, 0.f);
      if (outf) outf[(size_t)n*C_DIM + col] = v;
      if (outb) outb[(size_t)n*C_DIM + col] = f2b(v);
    }
  }
}

// ---------------- ws layout (bytes) ----------------
static constexpr size_t X1_OFF  = 0;                         // bf16 x1: N*C*2 = 32,000,000
static constexpr size_t RP_OFF  = 32000000;                  // rowptr (N+1)*4
static constexpr size_t CUR_OFF = RP_OFF  + 400016;          // cursor N*4
static constexpr size_t DEG_OFF = CUR_OFF + 400000;          // deg N*4
static constexpr size_t SRC_OFF = DEG_OFF + 400000;          // srcs E*4
static constexpr size_t RELS_OFF= SRC_OFF + 2000000;         // rels E*4
static constexpr size_t SUM_OFF = RELS_OFF+ 2000000;         // scan sums
static constexpr size_t WP1_OFF = SUM_OFF + 128;             // 153,600 B
static constexpr size_t WP2_OFF = WP1_OFF + 153600;

extern "C" void kernel_launch(void* const* d_in, const int* in_sizes, int n_in,
                              void* d_out, int out_size, void* d_ws, size_t ws_size,
                              hipStream_t stream) {
  const float* node_emb = (const float*)d_in[0];
  const float* w1    = (const float*)d_in[1];
  const float* root1 = (const float*)d_in[2];
  const float* bias1 = (const float*)d_in[3];
  const float* w2    = (const float*)d_in[4];
  const float* root2 = (const float*)d_in[5];
  const float* bias2 = (const float*)d_in[6];
  const int*   ei    = (const int*)d_in[7];   // [2, E] : row0 = src, row1 = dst
  const int*   et    = (const int*)d_in[8];   // [E]

  char* ws = (char*)d_ws;
  unsigned short* x1   = (unsigned short*)(ws + X1_OFF);
  int* rowptr          = (int*)(ws + RP_OFF);
  int* cursor          = (int*)(ws + CUR_OFF);
  int* deg             = (int*)(ws + DEG_OFF);
  int* srcs            = (int*)(ws + SRC_OFF);
  int* rels            = (int*)(ws + RELS_OFF);
  int* sums            = (int*)(ws + SUM_OFF);
  unsigned short* wp1  = (unsigned short*)(ws + WP1_OFF);
  unsigned short* wp2  = (unsigned short*)(ws + WP2_OFF);

  const int* srcI = ei;
  const int* dstI = ei + E_EDGES;

  hipMemsetAsync(deg, 0, N_NODES*sizeof(int), stream);

  k_count  <<<(E_EDGES+255)/256, 256, 0, stream>>>(dstI, deg);
  k_scan1  <<<25, 256, 0, stream>>>(deg, rowptr, sums);
  k_scan2  <<<1, 1, 0, stream>>>(sums, rowptr, 25);
  k_scan3  <<<(N_NODES+255)/256, 256, 0, stream>>>(rowptr, cursor, sums);
  k_scatter<<<(E_EDGES+255)/256, 256, 0, stream>>>(srcI, dstI, et, cursor, srcs, rels);

  k_wpack<<<(9600+255)/256, 256, 0, stream>>>(w1, root1, wp1);
  k_wpack<<<(9600+255)/256, 256, 0, stream>>>(w2, root2, wp2);

  k_layer<1,1><<<N_NODES/NB, 256, 0, stream>>>(node_emb, nullptr, rowptr, srcs, rels,
                                               wp1, bias1, nullptr, x1);
  k_layer<0,0><<<N_NODES/NB, 256, 0, stream>>>(nullptr, x1, rowptr, srcs, rels,
                                               wp2, bias2, (float*)d_out, nullptr);
}

// Round 3
// 427.131 us; speedup vs baseline: 1.9511x; 1.9511x over previous
//
#include <hip/hip_runtime.h>
#include <hip/hip_bf16.h>

#define N_NODES 100000
#define C_DIM   160
#define R_REL   10
#define B_BLK   5
#define CB      32
#define E_EDGES 500000
#define M_SEG   (N_NODES*R_REL)   // 1,000,000 (dst,rel) segments
#define NB      16                // nodes per block (1 per wave, 16 waves)
#define ASTRIDE 1768              // ushorts per node row in LDS (221*16B, odd 16B stride)

typedef float f32x4 __attribute__((ext_vector_type(4)));
typedef short s16x8 __attribute__((ext_vector_type(8)));

__device__ __forceinline__ float b2f(unsigned short h){ return __uint_as_float(((unsigned)h)<<16); }
__device__ __forceinline__ unsigned short f2b(float f){
  unsigned b = __float_as_uint(f);
  b += 0x7FFFu + ((b>>16)&1u);            // round-to-nearest-even
  return (unsigned short)(b>>16);
}
__device__ __forceinline__ float4 unpack4(uint2 u){
  return make_float4(b2f((unsigned short)(u.x & 0xFFFF)), b2f((unsigned short)(u.x >> 16)),
                     b2f((unsigned short)(u.y & 0xFFFF)), b2f((unsigned short)(u.y >> 16)));
}

// ---------------- CSR build over (dst,rel) segments ----------------
__global__ __launch_bounds__(256) void k_count(const int* __restrict__ dst, const int* __restrict__ et,
                                               int* __restrict__ deg){
  int e = blockIdx.x*256 + threadIdx.x;
  if (e < E_EDGES) atomicAdd(&deg[dst[e]*R_REL + et[e]], 1);
}

__global__ __launch_bounds__(256) void k_scan1(const int* __restrict__ deg, int* __restrict__ rowptr,
                                               int* __restrict__ sums){
  __shared__ int lds[256];
  const int t = threadIdx.x;
  const int base = blockIdx.x*4096 + t*16;
  int v[16]; int tot = 0;
  #pragma unroll
  for (int i=0;i<16;++i){
    int idx = base+i;
    int d = (idx < M_SEG) ? deg[idx] : 0;
    v[i] = tot; tot += d;
  }
  lds[t] = tot;
  __syncthreads();
  for (int off=1; off<256; off<<=1){
    int x = (t>=off) ? lds[t-off] : 0;
    __syncthreads();
    lds[t] += x;
    __syncthreads();
  }
  const int excl = lds[t] - tot;
  #pragma unroll
  for (int i=0;i<16;++i){
    int idx = base+i;
    if (idx < M_SEG) rowptr[idx] = excl + v[i];
  }
  if (t == 0) sums[blockIdx.x] = lds[255];
}

__global__ void k_scan2(int* __restrict__ sums, int* __restrict__ rowptr, int nchunks){
  if (threadIdx.x==0 && blockIdx.x==0){
    int run = 0;
    for (int b=0;b<nchunks;++b){ int s = sums[b]; sums[b] = run; run += s; }
    rowptr[M_SEG] = run;
  }
}

__global__ __launch_bounds__(256) void k_scan3(int* __restrict__ rowptr, int* __restrict__ cursor,
                                               const int* __restrict__ sums){
  int i = blockIdx.x*256 + threadIdx.x;
  if (i < M_SEG){
    int v = rowptr[i] + sums[i>>12];
    rowptr[i] = v;
    cursor[i] = v;
  }
}

__global__ __launch_bounds__(256) void k_scatter(const int* __restrict__ src, const int* __restrict__ dst,
                                                 const int* __restrict__ et, int* __restrict__ cursor,
                                                 int* __restrict__ srcs){
  int e = blockIdx.x*256 + threadIdx.x;
  if (e < E_EDGES){
    int seg = dst[e]*R_REL + et[e];
    int pos = atomicAdd(&cursor[seg], 1);
    srcs[pos] = src[e];
  }
}

// ---------------- weight repack: B-fragment layout ----------------
// wp[((ct*15+ko)*64+lane)*8 + j] = B[k][col] with col = ct*16+(lane&15), k = ko*32+(lane>>4)*8+j
// k < 320: relation part (r = ko), block b = col/32, d = col%32 -> w[r][b][k%32][d]
// k >= 320: root part ci = k-320 -> root[ci][col]
__global__ __launch_bounds__(256) void k_wpack(const float* __restrict__ w, const float* __restrict__ root,
                                               unsigned short* __restrict__ wp){
  int tid = blockIdx.x*256 + threadIdx.x;
  if (tid >= 10*15*64) return;
  const int l  = tid & 63;
  const int ko = (tid>>6) % 15;
  const int ct = tid / (15*64);
  const int col16 = l & 15, kq = l >> 4;
  const int cout = ct*16 + col16;
  const int b = cout >> 5, d = cout & 31;
  unsigned short* dstp = wp + (size_t)tid*8;
  #pragma unroll
  for (int j=0;j<8;++j){
    float f;
    if (ko < 10){
      int cl = kq*8 + j;
      f = w[((ko*B_BLK + b)*CB + cl)*CB + d];
    } else {
      int ci = (ko-10)*32 + kq*8 + j;
      f = root[ci*C_DIM + cout];
    }
    dstp[j] = f2b(f);
  }
}

// ---------------- fused layer: aggregate + mean + (blockdiag ⊕ root) GEMM via MFMA ----------------
// 1024 threads = 16 waves; wave w aggregates node nb+w (relation-grouped CSR, no switch);
// Phase B: waves 0..9 each do one 16-col tile, K=480 (15 MFMA).
template<int XF32, int RELU>
__global__ __launch_bounds__(1024, 8) void k_layer(
    const float* __restrict__ xf,            // fp32 features (layer 1)
    const unsigned short* __restrict__ xb,   // bf16 features (layer 2)
    const int* __restrict__ rowptr,          // (dst,rel) rowptr, M_SEG+1
    const int* __restrict__ srcs,
    const unsigned short* __restrict__ wpack,
    const float* __restrict__ bias,
    float* __restrict__ outf,
    unsigned short* __restrict__ outb)
{
  __shared__ unsigned short A[NB*ASTRIDE];
  const int tid  = threadIdx.x;
  const int wave = __builtin_amdgcn_readfirstlane(tid >> 6);  // 0..15, wave-uniform SGPR
  const int lane = tid & 63;
  const int nb   = blockIdx.x * NB;
  const int n    = nb + wave;
  const int m    = wave;
  const int lc   = (lane < 40) ? lane : (lane - 40);   // channel-quad index (clamped for idle lanes)

  // ---- Phase A: this wave aggregates node n. lane l<40 holds channels 4l..4l+3 (float4).
  int rp[11];
  #pragma unroll
  for (int i=0;i<11;++i) rp[i] = rowptr[n*R_REL + i];

  #pragma unroll 1
  for (int r=0;r<R_REL;++r){
    const int e0 = rp[r], e1 = rp[r+1];
    float4 acc = make_float4(0.f,0.f,0.f,0.f);
    int e = e0;
    for (; e+2<=e1; e+=2){          // unroll-2: two gathers in flight
      int s0 = srcs[e], s1 = srcs[e+1];
      float4 va, vb;
      if (XF32){
        va = ((const float4*)(xf + (size_t)s0*C_DIM))[lc];
        vb = ((const float4*)(xf + (size_t)s1*C_DIM))[lc];
      } else {
        va = unpack4(((const uint2*)(xb + (size_t)s0*C_DIM))[lc]);
        vb = unpack4(((const uint2*)(xb + (size_t)s1*C_DIM))[lc]);
      }
      acc.x += va.x+vb.x; acc.y += va.y+vb.y; acc.z += va.z+vb.z; acc.w += va.w+vb.w;
    }
    if (e < e1){
      int s0 = srcs[e];
      float4 va;
      if (XF32) va = ((const float4*)(xf + (size_t)s0*C_DIM))[lc];
      else      va = unpack4(((const uint2*)(xb + (size_t)s0*C_DIM))[lc]);
      acc.x += va.x; acc.y += va.y; acc.z += va.z; acc.w += va.w;
    }
    const float scl = (e1 > e0) ? 1.0f/(float)(e1-e0) : 0.f;
    if (lane < 40){
      uint2 wv;
      wv.x = (unsigned)f2b(acc.x*scl) | ((unsigned)f2b(acc.y*scl) << 16);
      wv.y = (unsigned)f2b(acc.z*scl) | ((unsigned)f2b(acc.w*scl) << 16);
      *(uint2*)&A[m*ASTRIDE + r*C_DIM + 4*lane] = wv;
    }
  }
  { // root row: x[n] at K-offset 1600
    float4 v;
    if (XF32) v = ((const float4*)(xf + (size_t)n*C_DIM))[lc];
    else      v = unpack4(((const uint2*)(xb + (size_t)n*C_DIM))[lc]);
    if (lane < 40){
      uint2 wv;
      wv.x = (unsigned)f2b(v.x) | ((unsigned)f2b(v.y) << 16);
      wv.y = (unsigned)f2b(v.z) | ((unsigned)f2b(v.w) << 16);
      *(uint2*)&A[m*ASTRIDE + 1600 + 4*lane] = wv;
    }
  }
  __syncthreads();

  // ---- Phase B: waves 0..9 -> col-tile ct = wave ; K = 480 (15 MFMA steps)
  if (wave < 10){
    const int ct = wave;
    const int b = ct >> 1;
    const int row16 = lane & 15;   // A row (node) / D col
    const int kq    = lane >> 4;   // k-chunk
    f32x4 c = {0.f, 0.f, 0.f, 0.f};
    #pragma unroll
    for (int ko=0; ko<15; ++ko){
      const int aoff = row16*ASTRIDE + (ko < 10 ? ko*C_DIM + b*CB + kq*8
                                                : 1600 + (ko-10)*CB + kq*8);
      s16x8 af  = *(const s16x8*)&A[aoff];
      s16x8 bfv = *(const s16x8*)&wpack[(size_t)((ct*15+ko)*64 + lane)*8];
      c = __builtin_amdgcn_mfma_f32_16x16x32_bf16(af, bfv, c, 0, 0, 0);
    }
    const int col = ct*16 + row16;
    const float bv = bias[col];
    #pragma unroll
    for (int q=0;q<4;++q){
      const int nn = nb + kq*4 + q;          // D row = (lane>>4)*4 + q
      float v = c[q] + bv;
      if (RELU) v = fmaxf(v, 0.f);
      if (outf) outf[(size_t)nn*C_DIM + col] = v;
      if (outb) outb[(size_t)nn*C_DIM + col] = f2b(v);
    }
  }
}

// ---------------- ws layout (bytes) ----------------
static constexpr size_t X1_OFF  = 0;                          // bf16 x1: N*C*2 = 32,000,000
static constexpr size_t RP_OFF  = 32000000;                   // rowptr (M_SEG+1)*4 = 4,000,016
static constexpr size_t DC_OFF  = RP_OFF + 4000016;           // deg/cursor (aliased) M_SEG*4
static constexpr size_t SRC_OFF = DC_OFF + 4000000;           // srcs E*4
static constexpr size_t SUM_OFF = SRC_OFF + 2000000;          // scan sums (245 -> 1024 B)
static constexpr size_t WP1_OFF = SUM_OFF + 1024;             // 153,600 B
static constexpr size_t WP2_OFF = WP1_OFF + 153600;           // 153,600 B

extern "C" void kernel_launch(void* const* d_in, const int* in_sizes, int n_in,
                              void* d_out, int out_size, void* d_ws, size_t ws_size,
                              hipStream_t stream) {
  const float* node_emb = (const float*)d_in[0];
  const float* w1    = (const float*)d_in[1];
  const float* root1 = (const float*)d_in[2];
  const float* bias1 = (const float*)d_in[3];
  const float* w2    = (const float*)d_in[4];
  const float* root2 = (const float*)d_in[5];
  const float* bias2 = (const float*)d_in[6];
  const int*   ei    = (const int*)d_in[7];   // [2, E] : row0 = src, row1 = dst
  const int*   et    = (const int*)d_in[8];   // [E]

  char* ws = (char*)d_ws;
  unsigned short* x1   = (unsigned short*)(ws + X1_OFF);
  int* rowptr          = (int*)(ws + RP_OFF);
  int* degcur          = (int*)(ws + DC_OFF);
  int* srcs            = (int*)(ws + SRC_OFF);
  int* sums            = (int*)(ws + SUM_OFF);
  unsigned short* wp1  = (unsigned short*)(ws + WP1_OFF);
  unsigned short* wp2  = (unsigned short*)(ws + WP2_OFF);

  const int* srcI = ei;
  const int* dstI = ei + E_EDGES;

  const int nchunks = (M_SEG + 4095) / 4096;   // 245

  hipMemsetAsync(degcur, 0, (size_t)M_SEG*sizeof(int), stream);

  k_count  <<<(E_EDGES+255)/256, 256, 0, stream>>>(dstI, et, degcur);
  k_scan1  <<<nchunks, 256, 0, stream>>>(degcur, rowptr, sums);
  k_scan2  <<<1, 1, 0, stream>>>(sums, rowptr, nchunks);
  k_scan3  <<<(M_SEG+255)/256, 256, 0, stream>>>(rowptr, degcur, sums);
  k_scatter<<<(E_EDGES+255)/256, 256, 0, stream>>>(srcI, dstI, et, degcur, srcs);

  k_wpack<<<(9600+255)/256, 256, 0, stream>>>(w1, root1, wp1);
  k_wpack<<<(9600+255)/256, 256, 0, stream>>>(w2, root2, wp2);

  k_layer<1,1><<<N_NODES/NB, 1024, 0, stream>>>(node_emb, nullptr, rowptr, srcs,
                                                wp1, bias1, nullptr, x1);
  k_layer<0,0><<<N_NODES/NB, 1024, 0, stream>>>(nullptr, x1, rowptr, srcs,
                                                wp2, bias2, (float*)d_out, nullptr);
}

// Round 4
// 377.071 us; speedup vs baseline: 2.2101x; 1.1328x over previous
//
#include <hip/hip_runtime.h>
#include <hip/hip_bf16.h>

#define N_NODES 100000
#define C_DIM   160
#define R_REL   10
#define B_BLK   5
#define CB      32
#define E_EDGES 500000
#define M_SEG   (N_NODES*R_REL)   // 1,000,000 (dst,rel) segments
#define NB      16                // nodes per block (1 per wave, 16 waves)
#define ASTRIDE 1768              // ushorts per node row in LDS (221*16B: odd 16B stride -> 2-way max on b128)
#define NCHUNK  ((M_SEG + 4095)/4096)   // 245

typedef float f32x4 __attribute__((ext_vector_type(4)));
typedef short s16x8 __attribute__((ext_vector_type(8)));

__device__ __forceinline__ float b2f(unsigned short h){ return __uint_as_float(((unsigned)h)<<16); }
__device__ __forceinline__ unsigned pack2(float a, float b){
  union { __hip_bfloat162 h; unsigned u; } cv;
  cv.h = __float22bfloat162_rn(make_float2(a, b));   // v_cvt_pk_bf16_f32 (RNE)
  return cv.u;
}
__device__ __forceinline__ unsigned short f2b(float f){
  unsigned b = __float_as_uint(f);
  b += 0x7FFFu + ((b>>16)&1u);
  return (unsigned short)(b>>16);
}
__device__ __forceinline__ float4 unpack4(uint2 u){
  return make_float4(b2f((unsigned short)(u.x & 0xFFFF)), b2f((unsigned short)(u.x >> 16)),
                     b2f((unsigned short)(u.y & 0xFFFF)), b2f((unsigned short)(u.y >> 16)));
}

// ---------------- CSR build over (dst,rel) segments ----------------
__global__ __launch_bounds__(256) void k_count(const int* __restrict__ dst, const int* __restrict__ et,
                                               int* __restrict__ deg){
  int e = blockIdx.x*256 + threadIdx.x;
  if (e < E_EDGES) atomicAdd(&deg[dst[e]*R_REL + et[e]], 1);
}

__global__ __launch_bounds__(256) void k_scan1(const int* __restrict__ deg, int* __restrict__ rowptr,
                                               int* __restrict__ sums){
  __shared__ int lds[256];
  const int t = threadIdx.x;
  const int base = blockIdx.x*4096 + t*16;
  int v[16]; int tot = 0;
  #pragma unroll
  for (int i=0;i<16;++i){
    int idx = base+i;
    int d = (idx < M_SEG) ? deg[idx] : 0;
    v[i] = tot; tot += d;
  }
  lds[t] = tot;
  __syncthreads();
  for (int off=1; off<256; off<<=1){
    int x = (t>=off) ? lds[t-off] : 0;
    __syncthreads();
    lds[t] += x;
    __syncthreads();
  }
  const int excl = lds[t] - tot;
  #pragma unroll
  for (int i=0;i<16;++i){
    int idx = base+i;
    if (idx < M_SEG) rowptr[idx] = excl + v[i];
  }
  if (t == 0) sums[blockIdx.x] = lds[255];
}

// parallel scan of the NCHUNK partials (one 256-thread block)
__global__ __launch_bounds__(256) void k_scan2(int* __restrict__ sums, int* __restrict__ rowptr){
  __shared__ int lds[256];
  const int t = threadIdx.x;
  const int v = (t < NCHUNK) ? sums[t] : 0;
  lds[t] = v;
  __syncthreads();
  for (int off=1; off<256; off<<=1){
    int x = (t>=off) ? lds[t-off] : 0;
    __syncthreads();
    lds[t] += x;
    __syncthreads();
  }
  if (t < NCHUNK) sums[t] = lds[t] - v;          // exclusive prefix of chunk totals
  if (t == NCHUNK-1) rowptr[M_SEG] = lds[t];     // grand total
}

__global__ __launch_bounds__(256) void k_scan3(int* __restrict__ rowptr, int* __restrict__ cursor,
                                               const int* __restrict__ sums){
  int i = blockIdx.x*256 + threadIdx.x;
  if (i < M_SEG){
    int v = rowptr[i] + sums[i>>12];
    rowptr[i] = v;
    cursor[i] = v;
  }
}

__global__ __launch_bounds__(256) void k_scatter(const int* __restrict__ src, const int* __restrict__ dst,
                                                 const int* __restrict__ et, int* __restrict__ cursor,
                                                 int* __restrict__ srcs){
  int e = blockIdx.x*256 + threadIdx.x;
  if (e < E_EDGES){
    int seg = dst[e]*R_REL + et[e];
    int pos = atomicAdd(&cursor[seg], 1);
    srcs[pos] = src[e];
  }
}

// ---------------- weight repack (both layers in one launch): B-fragment layout ----------------
// wp[((ct*15+ko)*64+lane)*8 + j] = B[k][col], col = ct*16+(lane&15), k = ko*32+(lane>>4)*8+j
// k<320: w[r=ko][b=col/32][k%32][col%32] ; k>=320: root[k-320][col]
__global__ __launch_bounds__(256) void k_wpack(const float* __restrict__ w1, const float* __restrict__ root1,
                                               unsigned short* __restrict__ wp1,
                                               const float* __restrict__ w2, const float* __restrict__ root2,
                                               unsigned short* __restrict__ wp2){
  int tid0 = blockIdx.x*256 + threadIdx.x;
  if (tid0 >= 2*10*15*64) return;
  const int which = (tid0 >= 9600);
  const int tid = which ? tid0 - 9600 : tid0;
  const float* w    = which ? w2 : w1;
  const float* root = which ? root2 : root1;
  unsigned short* wp = which ? wp2 : wp1;
  const int l  = tid & 63;
  const int ko = (tid>>6) % 15;
  const int ct = tid / (15*64);
  const int col16 = l & 15, kq = l >> 4;
  const int cout = ct*16 + col16;
  const int b = cout >> 5, d = cout & 31;
  unsigned short* dstp = wp + (size_t)tid*8;
  #pragma unroll
  for (int j=0;j<8;++j){
    float f;
    if (ko < 10){
      int cl = kq*8 + j;
      f = w[((ko*B_BLK + b)*CB + cl)*CB + d];
    } else {
      int ci = (ko-10)*32 + kq*8 + j;
      f = root[ci*C_DIM + cout];
    }
    dstp[j] = f2b(f);
  }
}

// ---------------- fused layer: aggregate + mean + (blockdiag ⊕ root) GEMM via MFMA ----------------
// 1024 threads = 16 waves; wave w aggregates node nb+w (relation-grouped CSR);
// Phase B: waves 0..9 each do one 16-col tile, K=480 (15 MFMA).
template<int XF32, int RELU>
__global__ __launch_bounds__(1024, 8) void k_layer(
    const float* __restrict__ xf,            // fp32 features (layer 1)
    const unsigned short* __restrict__ xb,   // bf16 features (layer 2)
    const int* __restrict__ rowptr,          // (dst,rel) rowptr, M_SEG+1
    const int* __restrict__ srcs,
    const unsigned short* __restrict__ wpack,
    const float* __restrict__ bias,
    float* __restrict__ outf,
    unsigned short* __restrict__ outb)
{
  __shared__ unsigned short A[NB*ASTRIDE];
  const int tid  = threadIdx.x;
  const int wave = __builtin_amdgcn_readfirstlane(tid >> 6);  // 0..15, wave-uniform
  const int lane = tid & 63;
  const int nb   = blockIdx.x * NB;
  const int n    = nb + wave;
  const int m    = wave;
  const int lc   = (lane < 40) ? lane : (lane - 40);   // channel-quad index

  // ---- Phase A: wave aggregates node n; lane l<40 holds channels 4l..4l+3.
  int rp[11];
  #pragma unroll
  for (int i=0;i<11;++i) rp[i] = rowptr[n*R_REL + i];

  #pragma unroll
  for (int r=0;r<R_REL;++r){
    const int e0 = rp[r], e1 = rp[r+1];
    unsigned short* rowp = &A[m*ASTRIDE + r*C_DIM];
    if (e1 == e0){                         // empty segment: mean = 0 (wave-uniform branch)
      if (lane < 40) *(uint2*)&rowp[4*lane] = make_uint2(0u, 0u);
      continue;
    }
    float4 acc = make_float4(0.f,0.f,0.f,0.f);
    int e = e0;
    for (; e+2<=e1; e+=2){                 // two gathers in flight
      int s0 = srcs[e], s1 = srcs[e+1];
      float4 va, vb;
      if (XF32){
        va = ((const float4*)(xf + (size_t)s0*C_DIM))[lc];
        vb = ((const float4*)(xf + (size_t)s1*C_DIM))[lc];
      } else {
        va = unpack4(((const uint2*)(xb + (size_t)s0*C_DIM))[lc]);
        vb = unpack4(((const uint2*)(xb + (size_t)s1*C_DIM))[lc]);
      }
      acc.x += va.x+vb.x; acc.y += va.y+vb.y; acc.z += va.z+vb.z; acc.w += va.w+vb.w;
    }
    if (e < e1){
      int s0 = srcs[e];
      float4 va;
      if (XF32) va = ((const float4*)(xf + (size_t)s0*C_DIM))[lc];
      else      va = unpack4(((const uint2*)(xb + (size_t)s0*C_DIM))[lc]);
      acc.x += va.x; acc.y += va.y; acc.z += va.z; acc.w += va.w;
    }
    const float scl = 1.0f/(float)(e1-e0);
    if (lane < 40){
      uint2 wv;
      wv.x = pack2(acc.x*scl, acc.y*scl);
      wv.y = pack2(acc.z*scl, acc.w*scl);
      *(uint2*)&rowp[4*lane] = wv;
    }
  }
  { // root row: x[n] at K-offset 1600
    float4 v;
    if (XF32) v = ((const float4*)(xf + (size_t)n*C_DIM))[lc];
    else      v = unpack4(((const uint2*)(xb + (size_t)n*C_DIM))[lc]);
    if (lane < 40){
      uint2 wv;
      wv.x = pack2(v.x, v.y);
      wv.y = pack2(v.z, v.w);
      *(uint2*)&A[m*ASTRIDE + 1600 + 4*lane] = wv;
    }
  }
  __syncthreads();

  // ---- Phase B: waves 0..9 -> col-tile ct = wave ; K = 480 (15 MFMA steps)
  if (wave < 10){
    const int ct = wave;
    const int b = ct >> 1;
    const int row16 = lane & 15;   // A row (node) / D col
    const int kq    = lane >> 4;   // k-chunk
    f32x4 c = {0.f, 0.f, 0.f, 0.f};
    #pragma unroll
    for (int ko=0; ko<15; ++ko){
      const int aoff = row16*ASTRIDE + (ko < 10 ? ko*C_DIM + b*CB + kq*8
                                                : 1600 + (ko-10)*CB + kq*8);
      s16x8 af  = *(const s16x8*)&A[aoff];
      s16x8 bfv = *(const s16x8*)&wpack[(size_t)((ct*15+ko)*64 + lane)*8];
      c = __builtin_amdgcn_mfma_f32_16x16x32_bf16(af, bfv, c, 0, 0, 0);
    }
    const int col = ct*16 + row16;
    const float bv = bias[col];
    #pragma unroll
    for (int q=0;q<4;++q){
      const int nn = nb + kq*4 + q;          // D row = (lane>>4)*4 + q
      float v = c[q] + bv;
      if (RELU) v = fmaxf(v, 0.f);
      if (outf) outf[(size_t)nn*C_DIM + col] = v;
      if (outb) outb[(size_t)nn*C_DIM + col] = f2b(v);
    }
  }
}

// ---------------- ws layout (bytes) ----------------
static constexpr size_t X1_OFF  = 0;                          // bf16 x1: N*C*2 = 32,000,000
static constexpr size_t RP_OFF  = 32000000;                   // rowptr (M_SEG+1)*4 = 4,000,016
static constexpr size_t DC_OFF  = RP_OFF + 4000016;           // deg/cursor (aliased) M_SEG*4
static constexpr size_t SRC_OFF = DC_OFF + 4000000;           // srcs E*4
static constexpr size_t SUM_OFF = SRC_OFF + 2000000;          // scan sums (245 -> 1024 B)
static constexpr size_t WP1_OFF = SUM_OFF + 1024;             // 153,600 B
static constexpr size_t WP2_OFF = WP1_OFF + 153600;           // 153,600 B

extern "C" void kernel_launch(void* const* d_in, const int* in_sizes, int n_in,
                              void* d_out, int out_size, void* d_ws, size_t ws_size,
                              hipStream_t stream) {
  const float* node_emb = (const float*)d_in[0];
  const float* w1    = (const float*)d_in[1];
  const float* root1 = (const float*)d_in[2];
  const float* bias1 = (const float*)d_in[3];
  const float* w2    = (const float*)d_in[4];
  const float* root2 = (const float*)d_in[5];
  const float* bias2 = (const float*)d_in[6];
  const int*   ei    = (const int*)d_in[7];   // [2, E] : row0 = src, row1 = dst
  const int*   et    = (const int*)d_in[8];   // [E]

  char* ws = (char*)d_ws;
  unsigned short* x1   = (unsigned short*)(ws + X1_OFF);
  int* rowptr          = (int*)(ws + RP_OFF);
  int* degcur          = (int*)(ws + DC_OFF);
  int* srcs            = (int*)(ws + SRC_OFF);
  int* sums            = (int*)(ws + SUM_OFF);
  unsigned short* wp1  = (unsigned short*)(ws + WP1_OFF);
  unsigned short* wp2  = (unsigned short*)(ws + WP2_OFF);

  const int* srcI = ei;
  const int* dstI = ei + E_EDGES;

  hipMemsetAsync(degcur, 0, (size_t)M_SEG*sizeof(int), stream);

  k_count  <<<(E_EDGES+255)/256, 256, 0, stream>>>(dstI, et, degcur);
  k_scan1  <<<NCHUNK, 256, 0, stream>>>(degcur, rowptr, sums);
  k_scan2  <<<1, 256, 0, stream>>>(sums, rowptr);
  k_scan3  <<<(M_SEG+255)/256, 256, 0, stream>>>(rowptr, degcur, sums);
  k_scatter<<<(E_EDGES+255)/256, 256, 0, stream>>>(srcI, dstI, et, degcur, srcs);

  k_wpack<<<(19200+255)/256, 256, 0, stream>>>(w1, root1, wp1, w2, root2, wp2);

  k_layer<1,1><<<N_NODES/NB, 1024, 0, stream>>>(node_emb, nullptr, rowptr, srcs,
                                                wp1, bias1, nullptr, x1);
  k_layer<0,0><<<N_NODES/NB, 1024, 0, stream>>>(nullptr, x1, rowptr, srcs,
                                                wp2, bias2, (float*)d_out, nullptr);
}

// Round 5
// 361.655 us; speedup vs baseline: 2.3043x; 1.0426x over previous
//
#include <hip/hip_runtime.h>
#include <hip/hip_bf16.h>

#define N_NODES 100000
#define C_DIM   160
#define R_REL   10
#define B_BLK   5
#define CB      32
#define E_EDGES 500000
#define M_SEG   (N_NODES*R_REL)   // 1,000,000 (dst,rel) segments
#define NB      16                // nodes per block (1 per wave, 16 waves)
#define ASTRIDE 1768              // ushorts per node row in LDS (221*16B: odd 16B stride)
#define NCHUNK  ((M_SEG + 4095)/4096)   // 245

typedef float f32x4 __attribute__((ext_vector_type(4)));
typedef short s16x8 __attribute__((ext_vector_type(8)));

__device__ __forceinline__ float b2f(unsigned short h){ return __uint_as_float(((unsigned)h)<<16); }
__device__ __forceinline__ unsigned pack2(float a, float b){
  union { __hip_bfloat162 h; unsigned u; } cv;
  cv.h = __float22bfloat162_rn(make_float2(a, b));   // v_cvt_pk_bf16_f32 (RNE)
  return cv.u;
}
__device__ __forceinline__ unsigned short f2b(float f){
  unsigned b = __float_as_uint(f);
  b += 0x7FFFu + ((b>>16)&1u);
  return (unsigned short)(b>>16);
}
__device__ __forceinline__ float4 unpack4(uint2 u){
  return make_float4(b2f((unsigned short)(u.x & 0xFFFF)), b2f((unsigned short)(u.x >> 16)),
                     b2f((unsigned short)(u.y & 0xFFFF)), b2f((unsigned short)(u.y >> 16)));
}

// ---------------- fp32 -> bf16 feature convert (8 elems/thread) ----------------
__global__ __launch_bounds__(256) void k_cvt(const float* __restrict__ in, unsigned short* __restrict__ out){
  const int i = blockIdx.x*256 + threadIdx.x;
  const int total = N_NODES*C_DIM/8;     // 2,000,000
  if (i < total){
    const float4* p = (const float4*)in + (size_t)i*2;
    float4 a = p[0], b = p[1];
    uint4 w;
    w.x = pack2(a.x, a.y); w.y = pack2(a.z, a.w);
    w.z = pack2(b.x, b.y); w.w = pack2(b.z, b.w);
    ((uint4*)out)[i] = w;
  }
}

// ---------------- CSR build over (dst,rel) segments ----------------
__global__ __launch_bounds__(256) void k_count(const int* __restrict__ dst, const int* __restrict__ et,
                                               int* __restrict__ deg){
  int e = blockIdx.x*256 + threadIdx.x;
  if (e < E_EDGES) atomicAdd(&deg[dst[e]*R_REL + et[e]], 1);
}

__global__ __launch_bounds__(256) void k_scan1(const int* __restrict__ deg, int* __restrict__ rowptr,
                                               int* __restrict__ sums){
  __shared__ int lds[256];
  const int t = threadIdx.x;
  const int base = blockIdx.x*4096 + t*16;
  int v[16]; int tot = 0;
  #pragma unroll
  for (int i=0;i<16;++i){
    int idx = base+i;
    int d = (idx < M_SEG) ? deg[idx] : 0;
    v[i] = tot; tot += d;
  }
  lds[t] = tot;
  __syncthreads();
  for (int off=1; off<256; off<<=1){
    int x = (t>=off) ? lds[t-off] : 0;
    __syncthreads();
    lds[t] += x;
    __syncthreads();
  }
  const int excl = lds[t] - tot;
  #pragma unroll
  for (int i=0;i<16;++i){
    int idx = base+i;
    if (idx < M_SEG) rowptr[idx] = excl + v[i];
  }
  if (t == 0) sums[blockIdx.x] = lds[255];
}

__global__ __launch_bounds__(256) void k_scan2(int* __restrict__ sums, int* __restrict__ rowptr){
  __shared__ int lds[256];
  const int t = threadIdx.x;
  const int v = (t < NCHUNK) ? sums[t] : 0;
  lds[t] = v;
  __syncthreads();
  for (int off=1; off<256; off<<=1){
    int x = (t>=off) ? lds[t-off] : 0;
    __syncthreads();
    lds[t] += x;
    __syncthreads();
  }
  if (t < NCHUNK) sums[t] = lds[t] - v;          // exclusive prefix of chunk totals
  if (t == NCHUNK-1) rowptr[M_SEG] = lds[t];     // grand total
}

__global__ __launch_bounds__(256) void k_scan3(int* __restrict__ rowptr, int* __restrict__ cursor,
                                               const int* __restrict__ sums){
  int i = blockIdx.x*256 + threadIdx.x;
  if (i < M_SEG){
    int v = rowptr[i] + sums[i>>12];
    rowptr[i] = v;
    cursor[i] = v;
  }
}

// scatter packed (src | rel<<20) into (dst,rel)-sorted order
__global__ __launch_bounds__(256) void k_scatter(const int* __restrict__ src, const int* __restrict__ dst,
                                                 const int* __restrict__ et, int* __restrict__ cursor,
                                                 unsigned* __restrict__ pked){
  int e = blockIdx.x*256 + threadIdx.x;
  if (e < E_EDGES){
    int r = et[e];
    int seg = dst[e]*R_REL + r;
    int pos = atomicAdd(&cursor[seg], 1);
    pked[pos] = (unsigned)src[e] | ((unsigned)r << 20);
  }
}

// ---------------- weight repack (both layers): B-fragment layout ----------------
// wp[((ct*15+ko)*64+lane)*8 + j] = B[k][col], col = ct*16+(lane&15), k = ko*32+(lane>>4)*8+j
// k<320: w[r=ko][b=col/32][k%32][col%32] ; k>=320: root[k-320][col]
__global__ __launch_bounds__(256) void k_wpack(const float* __restrict__ w1, const float* __restrict__ root1,
                                               unsigned short* __restrict__ wp1,
                                               const float* __restrict__ w2, const float* __restrict__ root2,
                                               unsigned short* __restrict__ wp2){
  int tid0 = blockIdx.x*256 + threadIdx.x;
  if (tid0 >= 2*10*15*64) return;
  const int which = (tid0 >= 9600);
  const int tid = which ? tid0 - 9600 : tid0;
  const float* w    = which ? w2 : w1;
  const float* root = which ? root2 : root1;
  unsigned short* wp = which ? wp2 : wp1;
  const int l  = tid & 63;
  const int ko = (tid>>6) % 15;
  const int ct = tid / (15*64);
  const int col16 = l & 15, kq = l >> 4;
  const int cout = ct*16 + col16;
  const int b = cout >> 5, d = cout & 31;
  unsigned short* dstp = wp + (size_t)tid*8;
  #pragma unroll
  for (int j=0;j<8;++j){
    float f;
    if (ko < 10){
      int cl = kq*8 + j;
      f = w[((ko*B_BLK + b)*CB + cl)*CB + d];
    } else {
      int ci = (ko-10)*32 + kq*8 + j;
      f = root[ci*C_DIM + cout];
    }
    dstp[j] = f2b(f);
  }
}

// ---------------- fused layer ----------------
// 1024 threads = 16 waves; wave w aggregates node nb+w.
// Phase A: one lane-parallel load of packed edges, then readlane -> 4 row-gathers in
// flight; per-relation mean via flush-on-rel-change (runs are contiguous: CSR is
// (dst,rel)-sorted). Phase B: waves 0..9 one 16-col tile each, K=480 (15 MFMA).
template<int XF32, int RELU>
__global__ __launch_bounds__(1024, 8) void k_layer(
    const float* __restrict__ xf,            // fp32 features (fallback path)
    const unsigned short* __restrict__ xb,   // bf16 features
    const int* __restrict__ rowptr,          // (dst,rel) rowptr, M_SEG+1
    const unsigned* __restrict__ pked,       // packed src|rel<<20
    const unsigned short* __restrict__ wpack,
    const float* __restrict__ bias,
    float* __restrict__ outf,
    unsigned short* __restrict__ outb)
{
  __shared__ unsigned short A[NB*ASTRIDE];
  const int tid  = threadIdx.x;
  const int wave = __builtin_amdgcn_readfirstlane(tid >> 6);
  const int lane = tid & 63;
  const int nb   = blockIdx.x * NB;
  const int n    = nb + wave;
  const int m    = wave;
  const int lc   = (lane < 40) ? lane : (lane - 40);   // channel-quad index
  const bool act = (lane < 40);

  // pre-zero the 10 mean rows (covers empty segments)
  if (act){
    #pragma unroll
    for (int r=0;r<R_REL;++r)
      *(uint2*)&A[m*ASTRIDE + r*C_DIM + 4*lane] = make_uint2(0u,0u);
  }

  const int e0 = rowptr[n*R_REL];
  const int e1 = rowptr[n*R_REL + R_REL];

  int r_cur = -1, ecnt = 0;
  float4 acc = make_float4(0.f,0.f,0.f,0.f);

  for (int eb = e0; eb < e1; eb += 64){
    const int cnt = min(64, e1 - eb);
    unsigned pkl = (eb + lane < e1) ? pked[eb + lane] : 0u;
    int j = 0;
    for (; j + 4 <= cnt; j += 4){
      unsigned pk0 = (unsigned)__builtin_amdgcn_readlane((int)pkl, j+0);
      unsigned pk1 = (unsigned)__builtin_amdgcn_readlane((int)pkl, j+1);
      unsigned pk2 = (unsigned)__builtin_amdgcn_readlane((int)pkl, j+2);
      unsigned pk3 = (unsigned)__builtin_amdgcn_readlane((int)pkl, j+3);
      float4 g0, g1, g2, g3;
      if (XF32){
        g0 = ((const float4*)(xf + (size_t)(pk0 & 0xFFFFFu)*C_DIM))[lc];
        g1 = ((const float4*)(xf + (size_t)(pk1 & 0xFFFFFu)*C_DIM))[lc];
        g2 = ((const float4*)(xf + (size_t)(pk2 & 0xFFFFFu)*C_DIM))[lc];
        g3 = ((const float4*)(xf + (size_t)(pk3 & 0xFFFFFu)*C_DIM))[lc];
      } else {
        uint2 r0 = ((const uint2*)(xb + (size_t)(pk0 & 0xFFFFFu)*C_DIM))[lc];
        uint2 r1 = ((const uint2*)(xb + (size_t)(pk1 & 0xFFFFFu)*C_DIM))[lc];
        uint2 r2 = ((const uint2*)(xb + (size_t)(pk2 & 0xFFFFFu)*C_DIM))[lc];
        uint2 r3 = ((const uint2*)(xb + (size_t)(pk3 & 0xFFFFFu)*C_DIM))[lc];
        g0 = unpack4(r0); g1 = unpack4(r1); g2 = unpack4(r2); g3 = unpack4(r3);
      }
      #pragma unroll
      for (int u=0;u<4;++u){
        unsigned pk = (u==0)?pk0:(u==1)?pk1:(u==2)?pk2:pk3;
        float4  g  = (u==0)?g0 :(u==1)?g1 :(u==2)?g2 :g3;
        const int rl = (int)(pk >> 20);
        if (rl != r_cur){                      // uniform branch (readlane is uniform)
          if (r_cur >= 0){
            const float s = __builtin_amdgcn_rcpf((float)ecnt);
            if (act){
              uint2 wv; wv.x = pack2(acc.x*s, acc.y*s); wv.y = pack2(acc.z*s, acc.w*s);
              *(uint2*)&A[m*ASTRIDE + r_cur*C_DIM + 4*lane] = wv;
            }
          }
          r_cur = rl; ecnt = 0; acc = make_float4(0.f,0.f,0.f,0.f);
        }
        acc.x += g.x; acc.y += g.y; acc.z += g.z; acc.w += g.w; ecnt++;
      }
    }
    for (; j < cnt; ++j){
      unsigned pk = (unsigned)__builtin_amdgcn_readlane((int)pkl, j);
      float4 g;
      if (XF32) g = ((const float4*)(xf + (size_t)(pk & 0xFFFFFu)*C_DIM))[lc];
      else      g = unpack4(((const uint2*)(xb + (size_t)(pk & 0xFFFFFu)*C_DIM))[lc]);
      const int rl = (int)(pk >> 20);
      if (rl != r_cur){
        if (r_cur >= 0){
          const float s = __builtin_amdgcn_rcpf((float)ecnt);
          if (act){
            uint2 wv; wv.x = pack2(acc.x*s, acc.y*s); wv.y = pack2(acc.z*s, acc.w*s);
            *(uint2*)&A[m*ASTRIDE + r_cur*C_DIM + 4*lane] = wv;
          }
        }
        r_cur = rl; ecnt = 0; acc = make_float4(0.f,0.f,0.f,0.f);
      }
      acc.x += g.x; acc.y += g.y; acc.z += g.z; acc.w += g.w; ecnt++;
    }
  }
  if (r_cur >= 0){
    const float s = __builtin_amdgcn_rcpf((float)ecnt);
    if (act){
      uint2 wv; wv.x = pack2(acc.x*s, acc.y*s); wv.y = pack2(acc.z*s, acc.w*s);
      *(uint2*)&A[m*ASTRIDE + r_cur*C_DIM + 4*lane] = wv;
    }
  }
  { // root row: x[n] at K-offset 1600
    if (XF32){
      float4 v = ((const float4*)(xf + (size_t)n*C_DIM))[lc];
      if (act){
        uint2 wv; wv.x = pack2(v.x, v.y); wv.y = pack2(v.z, v.w);
        *(uint2*)&A[m*ASTRIDE + 1600 + 4*lane] = wv;
      }
    } else {
      uint2 rw = ((const uint2*)(xb + (size_t)n*C_DIM))[lc];
      if (act) *(uint2*)&A[m*ASTRIDE + 1600 + 4*lane] = rw;
    }
  }
  __syncthreads();

  // ---- Phase B: waves 0..9 -> col-tile ct = wave ; K = 480 (15 MFMA steps)
  if (wave < 10){
    const int ct = wave;
    const int b = ct >> 1;
    const int row16 = lane & 15;   // A row (node) / D col
    const int kq    = lane >> 4;   // k-chunk
    f32x4 c = {0.f, 0.f, 0.f, 0.f};
    #pragma unroll
    for (int ko=0; ko<15; ++ko){
      const int aoff = row16*ASTRIDE + (ko < 10 ? ko*C_DIM + b*CB + kq*8
                                                : 1600 + (ko-10)*CB + kq*8);
      s16x8 af  = *(const s16x8*)&A[aoff];
      s16x8 bfv = *(const s16x8*)&wpack[(size_t)((ct*15+ko)*64 + lane)*8];
      c = __builtin_amdgcn_mfma_f32_16x16x32_bf16(af, bfv, c, 0, 0, 0);
    }
    const int col = ct*16 + row16;
    const float bv = bias[col];
    #pragma unroll
    for (int q=0;q<4;++q){
      const int nn = nb + kq*4 + q;          // D row = (lane>>4)*4 + q
      float v = c[q] + bv;
      if (RELU) v = fmaxf(v, 0.f);
      if (outf) outf[(size_t)nn*C_DIM + col] = v;
      if (outb) outb[(size_t)nn*C_DIM + col] = f2b(v);
    }
  }
}

// ---------------- ws layout (bytes) ----------------
static constexpr size_t X1_OFF  = 0;                          // bf16 x1: 32,000,000
static constexpr size_t RP_OFF  = 32000000;                   // rowptr (M_SEG+1)*4
static constexpr size_t DC_OFF  = RP_OFF + 4000016;           // deg/cursor (aliased) M_SEG*4
static constexpr size_t PK_OFF  = DC_OFF + 4000000;           // packed edges E*4
static constexpr size_t SUM_OFF = PK_OFF + 2000000;           // scan sums
static constexpr size_t WP1_OFF = SUM_OFF + 1024;             // 153,600
static constexpr size_t WP2_OFF = WP1_OFF + 153600;           // 153,600
static constexpr size_t X0B_OFF = WP2_OFF + 153600;           // bf16 node_emb: 32,000,000
static constexpr size_t WS_NEED = X0B_OFF + 32000000;         // ~74.3 MB

extern "C" void kernel_launch(void* const* d_in, const int* in_sizes, int n_in,
                              void* d_out, int out_size, void* d_ws, size_t ws_size,
                              hipStream_t stream) {
  const float* node_emb = (const float*)d_in[0];
  const float* w1    = (const float*)d_in[1];
  const float* root1 = (const float*)d_in[2];
  const float* bias1 = (const float*)d_in[3];
  const float* w2    = (const float*)d_in[4];
  const float* root2 = (const float*)d_in[5];
  const float* bias2 = (const float*)d_in[6];
  const int*   ei    = (const int*)d_in[7];   // [2, E]: row0 = src, row1 = dst
  const int*   et    = (const int*)d_in[8];   // [E]

  char* ws = (char*)d_ws;
  unsigned short* x1   = (unsigned short*)(ws + X1_OFF);
  int* rowptr          = (int*)(ws + RP_OFF);
  int* degcur          = (int*)(ws + DC_OFF);
  unsigned* pked       = (unsigned*)(ws + PK_OFF);
  int* sums            = (int*)(ws + SUM_OFF);
  unsigned short* wp1  = (unsigned short*)(ws + WP1_OFF);
  unsigned short* wp2  = (unsigned short*)(ws + WP2_OFF);
  unsigned short* x0b  = (unsigned short*)(ws + X0B_OFF);

  const int* srcI = ei;
  const int* dstI = ei + E_EDGES;
  const bool use_cvt = (ws_size >= WS_NEED);   // host-side constant: identical work every call

  hipMemsetAsync(degcur, 0, (size_t)M_SEG*sizeof(int), stream);

  k_count  <<<(E_EDGES+255)/256, 256, 0, stream>>>(dstI, et, degcur);
  k_scan1  <<<NCHUNK, 256, 0, stream>>>(degcur, rowptr, sums);
  k_scan2  <<<1, 256, 0, stream>>>(sums, rowptr);
  k_scan3  <<<(M_SEG+255)/256, 256, 0, stream>>>(rowptr, degcur, sums);
  k_scatter<<<(E_EDGES+255)/256, 256, 0, stream>>>(srcI, dstI, et, degcur, pked);

  k_wpack<<<(19200+255)/256, 256, 0, stream>>>(w1, root1, wp1, w2, root2, wp2);

  if (use_cvt){
    k_cvt<<<(N_NODES*C_DIM/8 + 255)/256, 256, 0, stream>>>(node_emb, x0b);
    k_layer<0,1><<<N_NODES/NB, 1024, 0, stream>>>(nullptr, x0b, rowptr, pked,
                                                  wp1, bias1, nullptr, x1);
  } else {
    k_layer<1,1><<<N_NODES/NB, 1024, 0, stream>>>(node_emb, nullptr, rowptr, pked,
                                                  wp1, bias1, nullptr, x1);
  }
  k_layer<0,0><<<N_NODES/NB, 1024, 0, stream>>>(nullptr, x1, rowptr, pked,
                                                wp2, bias2, (float*)d_out, nullptr);
}